// Round 1
// baseline (78.073 us; speedup 1.0000x reference)
//
#include <hip/hip_runtime.h>
#include <math.h>

// KAN layer, fully fused single kernel (R6).
// R5 was: prep kernel materializes W[k,o]=sf*cp in a workspace, then a
// k-split GEMM kernel. rocprof showed both kernels are <40us each and the
// timed region is dominated by fixed costs (harness 256MiB poison fill at
// ~40us + TWO kernel launches). R6 removes the prep kernel and the W
// round-trip entirely: each thread owns whole i-columns (12 consecutive k),
// so cp[i][o][0..10] is read contiguously (3 overlapping 16B loads at
// offsets 0/4/7, 4B-aligned) and pre-scaled by sf in registers. The silu
// weight (=sf) is packed into the dead cp[7] lane so the inner loop is a
// pure 12-FMA dot per (row, output).

#define IN_DIM   128
#define OUT_DIM  128
#define NCP      11
#define GK       15
#define FS       12            // features per i: 11 bases + silu
#define KTOT     (IN_DIM * FS) // 1536
#define BT       8             // batch rows per block
#define OT       32            // outputs per block
#define VO       4             // outputs per thread
#define KSP      32            // k-split groups (one i per group-iter)
#define NI       (IN_DIM / KSP) // 4 i's per thread
#define THREADS  256
#define RPAD     260           // padded row stride for reduction scratch

typedef float f4v __attribute__((ext_vector_type(4)));
typedef f4v uf4 __attribute__((aligned(4)));   // 4B-aligned 16B vector load

__device__ __forceinline__ f4v ld4u(const float* __restrict__ p) {
    return *(const uf4*)p;                     // global_load_dwordx4, align 4
}

__global__ __launch_bounds__(THREADS, 2)
void kan_fused(const float* __restrict__ X,    // [B,128]
               const float* __restrict__ CP,   // [128,128,11]
               const float* __restrict__ SF,   // [128,128]
               const float* __restrict__ GR,   // [128,128,15]
               float* __restrict__ OUT)        // [B,128]
{
    __shared__ float F[BT * KTOT];             // 48 KiB -> 2 blocks/CU

    const int tid = threadIdx.x;
    const int b0  = blockIdx.x * BT;
    const int o0  = blockIdx.y * OT;

    // uniform knots (wave-uniform scalar loads; denominators are d*h)
    const float t0 = GR[0];
    const float h  = GR[1] - t0;
    const float r1 = 1.0f / h;
    const float r2 = 1.0f / (2.0f * h);
    const float r3 = 1.0f / (3.0f * h);
    float kn[GK];
    #pragma unroll
    for (int j = 0; j < GK; ++j) kn[j] = t0 + (float)j * h;

    // ---------------- Phase 1: features into LDS ----------------
    #pragma unroll
    for (int kq = 0; kq < (BT * IN_DIM) / THREADS; ++kq) {
        const int p = tid + kq * THREADS;     // (r,i)
        const int r = p >> 7;
        const int i = p & (IN_DIM - 1);

        const float x = X[(b0 + r) * IN_DIM + i];

        float b[GK - 1];
        #pragma unroll
        for (int j = 0; j < GK - 1; ++j)
            b[j] = (kn[j] <= x && x < kn[j + 1]) ? 1.0f : 0.0f;
        #pragma unroll
        for (int j = 0; j < GK - 2; ++j)
            b[j] = ((x - kn[j]) * b[j] + (kn[j + 2] - x) * b[j + 1]) * r1;
        #pragma unroll
        for (int j = 0; j < GK - 3; ++j)
            b[j] = ((x - kn[j]) * b[j] + (kn[j + 3] - x) * b[j + 1]) * r2;
        #pragma unroll
        for (int j = 0; j < GK - 4; ++j)
            b[j] = ((x - kn[j]) * b[j] + (kn[j + 4] - x) * b[j + 1]) * r3;

        const float silu = x / (1.0f + __expf(-x));

        float* f = &F[p * FS];
        *(float4*)(f + 0) = make_float4(b[0], b[1], b[2], b[3]);
        *(float4*)(f + 4) = make_float4(b[4], b[5], b[6], b[7]);
        *(float4*)(f + 8) = make_float4(b[8], b[9], b[10], silu);
    }
    __syncthreads();

    // ---------------- Phase 2: GEMM slice, weights straight from CP -----
    // thread = (ol in [0,8), ks in [0,32)); i = ks + 32*jj, jj=0..3.
    // Per i: 1 sf float4 + 12 cp 16B loads (offsets 0/4/7 per output),
    // pre-scale by sf in regs, then 8 rows x {3 ds_read_b128 + 48 FMA}.
    // LDS read banks: idx = 12*ks + c, 12*ks mod 32 distinct for ks 0..7
    // -> perfect 32-bank partition, 8-lane broadcast per address.
    const int ol = tid & (OT / VO - 1);        // 0..7
    const int ks = tid >> 3;                   // 0..31
    const int o4 = o0 + VO * ol;

    float acc[BT][VO];
    #pragma unroll
    for (int r = 0; r < BT; ++r)
        #pragma unroll
        for (int v = 0; v < VO; ++v) acc[r][v] = 0.0f;

    #pragma unroll
    for (int jj = 0; jj < NI; ++jj) {
        const int i = ks + KSP * jj;
        const float4 sf4 = *(const float4*)&SF[i * OUT_DIM + o4];
        const float* cb = CP + (i * OUT_DIM + o4) * NCP;

        // c[v][0] = sf_v*cp[0..3]; c[v][1] = sf_v*cp[4..7];
        // c[v][2] = (sf_v, sf_v*cp8, sf_v*cp9, sf_v*cp10)  (x = silu weight)
        f4v c[VO][3];
        #pragma unroll
        for (int v = 0; v < VO; ++v) {
            const float s = (v == 0) ? sf4.x : (v == 1) ? sf4.y
                          : (v == 2) ? sf4.z : sf4.w;
            const float* cv = cb + v * NCP;
            f4v a0 = ld4u(cv + 0);
            f4v a1 = ld4u(cv + 4);
            f4v a2 = ld4u(cv + 7);             // (cp7, cp8, cp9, cp10), in-bounds
            c[v][0] = s * a0;
            c[v][1] = s * a1;
            c[v][2].x = s;
            c[v][2].y = s * a2.y;
            c[v][2].z = s * a2.z;
            c[v][2].w = s * a2.w;
        }

        const int fb = i * FS;
        #pragma unroll
        for (int r = 0; r < BT; ++r) {
            const float4 f0 = *(const float4*)&F[r * KTOT + fb + 0]; // b0..b3
            const float4 f1 = *(const float4*)&F[r * KTOT + fb + 4]; // b4..b7
            const float4 f2 = *(const float4*)&F[r * KTOT + fb + 8]; // b8,b9,b10,silu
            #pragma unroll
            for (int v = 0; v < VO; ++v) {
                float a = acc[r][v];
                a = fmaf(f0.x, c[v][0].x, a);
                a = fmaf(f0.y, c[v][0].y, a);
                a = fmaf(f0.z, c[v][0].z, a);
                a = fmaf(f0.w, c[v][0].w, a);
                a = fmaf(f1.x, c[v][1].x, a);
                a = fmaf(f1.y, c[v][1].y, a);
                a = fmaf(f1.z, c[v][1].z, a);
                a = fmaf(f1.w, c[v][1].w, a);
                a = fmaf(f2.x, c[v][2].y, a);
                a = fmaf(f2.y, c[v][2].z, a);
                a = fmaf(f2.z, c[v][2].w, a);
                a = fmaf(f2.w, c[v][2].x, a);  // silu * sf
                acc[r][v] = a;
            }
        }
    }

    // ---------------- reduction over 32 k-slices (reuse F) --------------
    __syncthreads();
    float* red = F;                            // 32*RPAD*4 B = 33 KB < 48 KB
    #pragma unroll
    for (int r = 0; r < BT; ++r)
        *(float4*)&red[ks * RPAD + r * OT + VO * ol] =
            make_float4(acc[r][0], acc[r][1], acc[r][2], acc[r][3]);
    __syncthreads();

    {
        const int r  = tid >> 5;               // 0..7
        const int oc = tid & 31;               // 0..31
        float v = 0.0f;
        #pragma unroll
        for (int q = 0; q < KSP; ++q)
            v += red[q * RPAD + r * OT + oc];
        OUT[(b0 + r) * OUT_DIM + o0 + oc] = v; // coalesced 128B per r
    }
}

extern "C" void kernel_launch(void* const* d_in, const int* in_sizes, int n_in,
                              void* d_out, int out_size, void* d_ws, size_t ws_size,
                              hipStream_t stream) {
    const float* x  = (const float*)d_in[0];   // [B,128]
    const float* cp = (const float*)d_in[1];   // [128,128,11]
    const float* sf = (const float*)d_in[2];   // [128,128]
    const float* gr = (const float*)d_in[3];   // [128,128,15]
    float* out = (float*)d_out;
    (void)d_ws; (void)ws_size;                 // workspace no longer used

    const int batch = in_sizes[0] / IN_DIM;    // 1024

    dim3 grid(batch / BT, OUT_DIM / OT);       // (128,4) = 512 blocks
    kan_fused<<<grid, THREADS, 0, stream>>>(x, cp, sf, gr, out);
}